// Round 16
// baseline (1201.025 us; speedup 1.0000x reference)
//
#include <hip/hip_runtime.h>
#include <hip/hip_bf16.h>
#include <stdint.h>
#include <math.h>

// GPT-2-small forward. Inputs f32, compute bf16 MFMA w/ f32 accum, out f32.
// R15: head GEMM -> phase-split convoy (4 phases/K-step: {ds_read quadrant |
//      stage half-tile of t+1 | barrier | 16 MFMA | barrier}, boundary
//      vmcnt(0)+barrier), same 256x256/8w geometry + swizzles as R12.
//      All other kernels identical to R14.

#define L_ 6
#define H_ 12
#define C_ 768
#define T_ 1024
#define V_ 50257
#define VP2_ 50432
#define HD_ 64
#define BT_ 2048
#define F_ 3072
#define SCALE_ 0.03608439182435161f  // 768^-0.5 (reference scales by C, not HD)
#define NEGBIG_ -1e30f

typedef __bf16 bf;
typedef __attribute__((ext_vector_type(8))) __bf16 bf16x8;
typedef __attribute__((ext_vector_type(4))) __bf16 bf16x4;
typedef __attribute__((ext_vector_type(4))) float f32x4;

__device__ __forceinline__ void gload16(const void* g, void* l) {
  __builtin_amdgcn_global_load_lds(
      (const __attribute__((address_space(1))) unsigned int*)g,
      (__attribute__((address_space(3))) unsigned int*)l, 16, 0, 0);
}

__device__ __forceinline__ float gelu_f(float x) {
  return 0.5f * x * (1.0f + erff(x * 0.70710678118654752f));
}

// ---------------- embedding ----------------
__global__ __launch_bounds__(256) void embed_k(const int* __restrict__ tok,
                                               const float* __restrict__ te,
                                               const float* __restrict__ pe,
                                               float* __restrict__ x) {
  int bt = blockIdx.x;
  int c = blockIdx.y * 256 + threadIdx.x;
  int t = bt & (T_ - 1);
  int v = tok[bt];
  x[(size_t)bt * C_ + c] = te[(size_t)v * C_ + c] + pe[(size_t)t * C_ + c];
}

// ---------------- layernorm ----------------
__global__ __launch_bounds__(256) void ln_k(const float* __restrict__ xin,
                                            float* __restrict__ xout,
                                            bf* __restrict__ xb,
                                            const float* __restrict__ g,
                                            const float* __restrict__ b) {
  int row = blockIdx.x;
  const float* xr = xin + (size_t)row * C_;
  int tid = threadIdx.x;
  float v0 = xr[tid], v1 = xr[tid + 256], v2 = xr[tid + 512];
  float s1 = v0 + v1 + v2;
  float s2 = v0 * v0 + v1 * v1 + v2 * v2;
#pragma unroll
  for (int o = 32; o > 0; o >>= 1) {
    s1 += __shfl_xor(s1, o, 64);
    s2 += __shfl_xor(s2, o, 64);
  }
  __shared__ float r1[4], r2[4];
  int w = tid >> 6, lane = tid & 63;
  if (lane == 0) { r1[w] = s1; r2[w] = s2; }
  __syncthreads();
  float S1 = r1[0] + r1[1] + r1[2] + r1[3];
  float S2 = r2[0] + r2[1] + r2[2] + r2[3];
  float mean = S1 * (1.0f / C_);
  float var = S2 * (1.0f / C_) - mean * mean;
  float rs = rsqrtf(fmaxf(var, 0.0f) + 1e-5f);
  float* xo = xout + (size_t)row * C_;
  bf* xbo = xb + (size_t)row * C_;
  float vv[3] = {v0, v1, v2};
#pragma unroll
  for (int j = 0; j < 3; ++j) {
    int c = tid + j * 256;
    float o = (vv[j] - mean) * rs * g[c] + b[c];
    xo[c] = o;
    xbo[c] = (bf)o;
  }
}

// ------- 64x64 tiled transpose + f32->bf16: dst[n][k] = (bf)src[k][n] -------
__device__ __forceinline__ void transpose_body(const float* __restrict__ src,
                                               bf* __restrict__ dst, int src_ld,
                                               int dst_ld, int k0, int n0,
                                               int nmax) {
  __shared__ __align__(16) bf tl[64][72];
  int tid = threadIdx.x;
  int r = tid >> 2;
  int cb = (tid & 3) * 16;
#pragma unroll
  for (int j4 = 0; j4 < 4; ++j4) {
    int c = cb + j4 * 4;
    int n = n0 + c;
    size_t idx = (size_t)(k0 + r) * src_ld + n;
    const float* sp = src + idx;
    if (n + 4 <= nmax && (idx & 3) == 0) {
      f32x4 v = *(const f32x4*)sp;
      tl[r][c] = (bf)v[0];
      tl[r][c + 1] = (bf)v[1];
      tl[r][c + 2] = (bf)v[2];
      tl[r][c + 3] = (bf)v[3];
    } else {
#pragma unroll
      for (int j = 0; j < 4; ++j)
        tl[r][c + j] = (n + j < nmax) ? (bf)sp[j] : (bf)0.0f;
    }
  }
  __syncthreads();
  int n = n0 + r;
  bf16x8 w0, w1;
#pragma unroll
  for (int j = 0; j < 8; ++j) {
    w0[j] = tl[cb + j][r];
    w1[j] = tl[cb + 8 + j][r];
  }
  bf* dp = dst + (size_t)n * dst_ld + k0 + cb;
  *(bf16x8*)dp = w0;
  *(bf16x8*)(dp + 8) = w1;
}

__global__ __launch_bounds__(256) void transpose_k(const float* __restrict__ src,
                                                   bf* __restrict__ dst,
                                                   int src_ld, int dst_ld,
                                                   int nmax) {
  transpose_body(src, dst, src_ld, dst_ld, blockIdx.x * 64, blockIdx.y * 64,
                 nmax);
}

// per-layer weight transpose body: 1728 tiles/layer
__device__ __forceinline__ void trans_layer_body(
    int r, const float* __restrict__ Wq, const float* __restrict__ Wk,
    const float* __restrict__ Wv, const float* __restrict__ Wo,
    const float* __restrict__ W1, const float* __restrict__ W2,
    bf* __restrict__ wqkvT, bf* __restrict__ woT, bf* __restrict__ w1T,
    bf* __restrict__ w2T) {
  if (r < 432) {
    int z = r / 12, k0 = (r % 12) * 64;
    int tsel = z / H_, hh = z % H_;
    const float* W = (tsel == 0) ? Wq : (tsel == 1) ? Wk : Wv;
    transpose_body(W + (size_t)hh * C_ * HD_,
                   wqkvT + (size_t)(tsel * C_ + hh * HD_) * C_, HD_, C_, k0, 0,
                   HD_);
  } else if (r < 576) {
    r -= 432;
    transpose_body(Wo, woT, C_, C_, (r % 12) * 64, (r / 12) * 64, C_);
  } else if (r < 1152) {
    r -= 576;
    transpose_body(W1, w1T, F_, C_, (r % 12) * 64, (r / 12) * 64, F_);
  } else {
    r -= 1152;
    transpose_body(W2, w2T, C_, F_, (r % 48) * 64, (r / 48) * 64, C_);
  }
}

__global__ __launch_bounds__(256) void trans_layer_k(
    const float* __restrict__ Wq, const float* __restrict__ Wk,
    const float* __restrict__ Wv, const float* __restrict__ Wo,
    const float* __restrict__ W1, const float* __restrict__ W2,
    bf* __restrict__ wqkvT, bf* __restrict__ woT, bf* __restrict__ w1T,
    bf* __restrict__ w2T) {
  trans_layer_body(blockIdx.x, Wq, Wk, Wv, Wo, W1, W2, wqkvT, woT, w1T, w2T);
}

// all-layer weight transpose: grid 6*1728 (hoisted path)
__global__ __launch_bounds__(256) void trans_all_k(
    const float* __restrict__ Wq, const float* __restrict__ Wk,
    const float* __restrict__ Wv, const float* __restrict__ Wo,
    const float* __restrict__ W1, const float* __restrict__ W2,
    bf* __restrict__ wqkvT, bf* __restrict__ woT, bf* __restrict__ w1T,
    bf* __restrict__ w2T) {
  int l = blockIdx.x / 1728;
  int r = blockIdx.x % 1728;
  trans_layer_body(r, Wq + (size_t)l * H_ * C_ * HD_,
                   Wk + (size_t)l * H_ * C_ * HD_,
                   Wv + (size_t)l * H_ * C_ * HD_, Wo + (size_t)l * C_ * C_,
                   W1 + (size_t)l * C_ * F_, W2 + (size_t)l * F_ * C_,
                   wqkvT + (size_t)l * 3 * C_ * C_, woT + (size_t)l * C_ * C_,
                   w1T + (size_t)l * F_ * C_, w2T + (size_t)l * C_ * F_);
}

// ---------------- GEMM: C[2048][N] = A[2048][K] * Bt[N][K]^T ----------------
// (mid GEMMs; unchanged from R14)
template <int MODE, int BM, int BN, int NW, int KSPLIT>
__global__ __launch_bounds__(NW * 64) void gemm_bt(
    const bf* __restrict__ A, const bf* __restrict__ Bt,
    const float* __restrict__ bias, float* __restrict__ xres,
    bf* __restrict__ o0, bf* __restrict__ o1, bf* __restrict__ o2, int K) {
  constexpr int WM = BM / 2;
  constexpr int WN = BN / (NW / 2);
  constexpr int MI = WM / 16, NJ = WN / 16;
  constexpr int HALF = (BM + BN) * 64;
  __shared__ __align__(16) bf smem[2 * HALF];
  const int tid = threadIdx.x;
  const int w = tid >> 6, lane = tid & 63;
  const int wm = (NW == 8) ? (w >> 2) : (w >> 1);
  const int wn = (NW == 8) ? (w & 3) : (w & 1);
  const int lm = lane & 15, lg = lane >> 4;

  const int lin = blockIdx.y * gridDim.x + blockIdx.x;
  const int q8 = (gridDim.x * gridDim.y) >> 3;
  const int wg = (lin & 7) * q8 + (lin >> 3);
  const int mt = gridDim.y;
  const int m0 = (wg % mt) * BM, n0 = (wg / mt) * BN;

  const int kchunk = K / KSPLIT;
  const int kbase = (KSPLIT == 2) ? blockIdx.z * kchunk : 0;

  const int lr8 = lane >> 3;
  const int lc8s = ((lane & 7) ^ lr8) * 8;

  auto stage = [&](int buf, int k0) {
    bf* aL = smem + buf * HALF;
    bf* bL = aL + BM * 64;
#pragma unroll
    for (int c = 0; c < BM / (8 * NW); ++c) {
      int row = c * (8 * NW) + w * 8;
      gload16(A + (size_t)(m0 + row + lr8) * K + k0 + lc8s, &aL[row * 64]);
    }
#pragma unroll
    for (int c = 0; c < BN / (8 * NW); ++c) {
      int row = c * (8 * NW) + w * 8;
      gload16(Bt + (size_t)(n0 + row + lr8) * K + k0 + lc8s, &bL[row * 64]);
    }
  };

  f32x4 acc[MI][NJ];
#pragma unroll
  for (int i = 0; i < MI; ++i)
#pragma unroll
    for (int j = 0; j < NJ; ++j) acc[i][j] = (f32x4){0.f, 0.f, 0.f, 0.f};

  const int cXor = (lm & 7) * 8;
  const int NT = kchunk >> 6;
  stage(0, kbase);
  __syncthreads();
  int cur = 0;
  for (int t = 0; t < NT; ++t) {
    if (t + 1 < NT) stage(cur ^ 1, kbase + ((t + 1) << 6));
    const bf* aL = smem + cur * HALF;
    const bf* bL = aL + BM * 64;
#pragma unroll
    for (int ks = 0; ks < 2; ++ks) {
      const int cc = (ks * 32 + lg * 8) ^ cXor;
      bf16x8 af[MI], bfv[NJ];
#pragma unroll
      for (int i = 0; i < MI; ++i)
        af[i] = *(const bf16x8*)&aL[(wm * WM + i * 16 + lm) * 64 + cc];
#pragma unroll
      for (int j = 0; j < NJ; ++j)
        bfv[j] = *(const bf16x8*)&bL[(wn * WN + j * 16 + lm) * 64 + cc];
      __builtin_amdgcn_s_setprio(1);
#pragma unroll
      for (int i = 0; i < MI; ++i)
#pragma unroll
        for (int j = 0; j < NJ; ++j)
          acc[i][j] = __builtin_amdgcn_mfma_f32_16x16x32_bf16(
              af[i], bfv[j], acc[i][j], 0, 0, 0);
      __builtin_amdgcn_s_setprio(0);
    }
    __syncthreads();  // drains next-tile vmcnt + barrier
    cur ^= 1;
  }

  if constexpr (MODE == 0) {
    const int bb = m0 >> 10;
    if (n0 >= 2 * C_) {
      // V: stage [d][t] in LDS (stride BM+8), write 16B-coalesced v_t rows
      bf* sv = smem;
#pragma unroll
      for (int i = 0; i < MI; ++i)
#pragma unroll
        for (int j = 0; j < NJ; ++j) {
          int dl = wn * WN + j * 16 + lm;
#pragma unroll
          for (int r = 0; r < 4; ++r) {
            int tl = wm * WM + i * 16 + lg * 4 + r;
            sv[dl * (BM + 8) + tl] = (bf)acc[i][j][r];
          }
        }
      __syncthreads();
      int dd_l = tid >> 1, half = tid & 1;
      size_t vrow = (size_t)bb * C_ + (n0 - 2 * C_) + dd_l;
      int t_base = m0 & (T_ - 1);
#pragma unroll
      for (int s = 0; s < 4; ++s) {
        int tt = half * 32 + s * 8;
        *(bf16x8*)(o2 + vrow * T_ + t_base + tt) =
            *(const bf16x8*)&sv[dd_l * (BM + 8) + tt];
      }
      return;
    }
    // Q / K direct, j-inner
    bf* dst = (n0 < C_) ? o0 : o1;
    int nb = (n0 < C_) ? n0 : n0 - C_;
    size_t basej[NJ];
#pragma unroll
    for (int j = 0; j < NJ; ++j) {
      int rr = nb + wn * WN + j * 16 + lm;
      int hh = rr >> 6, dd = rr & 63;
      basej[j] = ((size_t)(bb * H_ + hh) * T_) * HD_ + dd;
    }
#pragma unroll
    for (int i = 0; i < MI; ++i)
#pragma unroll
      for (int r = 0; r < 4; ++r) {
        int tt = (m0 + wm * WM + i * 16 + lg * 4 + r) & (T_ - 1);
#pragma unroll
        for (int j = 0; j < NJ; ++j)
          dst[basej[j] + (size_t)tt * HD_] = (bf)acc[i][j][r];
      }
    return;
  }

  // MODE 1 / MODE 2, j-inner
  int ngj[NJ];
  float bv[NJ];
#pragma unroll
  for (int j = 0; j < NJ; ++j) {
    ngj[j] = n0 + wn * WN + j * 16 + lm;
    bv[j] = (KSPLIT == 1 || blockIdx.z == 0) ? bias[ngj[j]] : 0.f;
  }
#pragma unroll
  for (int i = 0; i < MI; ++i)
#pragma unroll
    for (int r = 0; r < 4; ++r) {
      int row = m0 + wm * WM + i * 16 + lg * 4 + r;
      if constexpr (MODE == 1) {
        float* xrow = xres + (size_t)row * C_;
#pragma unroll
        for (int j = 0; j < NJ; ++j) {
          if constexpr (KSPLIT == 2)
            atomicAdd(&xrow[ngj[j]], acc[i][j][r] + bv[j]);
          else
            xrow[ngj[j]] += acc[i][j][r] + bv[j];
        }
      } else {
        bf* orow = o0 + (size_t)row * F_;
#pragma unroll
        for (int j = 0; j < NJ; ++j)
          orow[ngj[j]] = (bf)gelu_f(acc[i][j][r] + bv[j]);
      }
    }
}

// -------- head GEMM: 256x256, 8 waves (2Mx4N), phase-split convoy ----------
// Per K-step (BK=64): 4 phases, each {ds_read quadrant | stage 1 half-tile
// of t+1 into buf^1 | barrier | 16 MFMA | barrier}; boundary vmcnt(0)+barrier.
// Stages never touch the buffer being read; all reads of buf complete before
// the boundary barrier; per-wave vmcnt(0) + barrier precede buf^1 reads.
__global__ __launch_bounds__(512) void gemm_head8(const bf* __restrict__ A,
                                                  const bf* __restrict__ Bt,
                                                  const float* __restrict__ bias,
                                                  float* __restrict__ out) {
  constexpr int K = C_, NT = C_ / 64;
  __shared__ __align__(16) bf smem[65536];  // 2 bufs x (A 256x64 + B 256x64)
  const int tid = threadIdx.x;
  const int w = tid >> 6, lane = tid & 63;
  const int wm = w >> 2, wn = w & 3;
  const int lm = lane & 15, lg = lane >> 4;

  const int lin = blockIdx.y * gridDim.x + blockIdx.x;
  const int q8 = (gridDim.x * gridDim.y) >> 3;
  const int wg = (lin & 7) * q8 + (lin >> 3);
  const int mt = gridDim.y;
  const int m0 = (wg % mt) * 256, n0 = (wg / mt) * 256;

  const int lr8 = lane >> 3;
  const int lc8s = ((lane & 7) ^ lr8) * 8;
  const int kx = lm & 7;

  // stage one 128x64 half-tile (2 gloads/thread)
  auto stageH = [&](int buf, int isB, int h, int kt) {
    bf* dst = smem + buf * 32768 + isB * 16384 + h * 8192;
    const bf* src = isB ? Bt : A;
    int b0 = isB ? n0 : m0;
#pragma unroll
    for (int r = 0; r < 2; ++r) {
      int row = r * 64 + w * 8;
      gload16(src + (size_t)(b0 + h * 128 + row + lr8) * K + kt * 64 + lc8s,
              dst + row * 64);
    }
  };

  f32x4 acc[8][4];
#pragma unroll
  for (int i = 0; i < 8; ++i)
#pragma unroll
    for (int j = 0; j < 4; ++j) acc[i][j] = (f32x4){0.f, 0.f, 0.f, 0.f};

  bf16x8 af[4][2], bfv[2][2];

  // prologue: stage all 4 half-tiles of K-tile 0
  stageH(0, 0, 0, 0);
  stageH(0, 0, 1, 0);
  stageH(0, 1, 0, 0);
  stageH(0, 1, 1, 0);
  __syncthreads();

#define RD_A(MH)                                                            \
  _Pragma("unroll") for (int i = 0; i < 4; ++i) _Pragma("unroll") for (      \
      int ks = 0; ks < 2; ++ks) af[i][ks] =                                  \
      *(const bf16x8*)&aBase[((MH)*64 + i * 16 + lm) * 64 +                  \
                             (((ks * 4 + lg) ^ kx) * 8)];
#define RD_B(NH)                                                            \
  _Pragma("unroll") for (int j = 0; j < 2; ++j) _Pragma("unroll") for (      \
      int ks = 0; ks < 2; ++ks) bfv[j][ks] =                                 \
      *(const bf16x8*)&bBase[((NH)*32 + j * 16 + lm) * 64 +                  \
                             (((ks * 4 + lg) ^ kx) * 8)];
#define MM16(MH, NH)                                                        \
  __builtin_amdgcn_s_setprio(1);                                            \
  _Pragma("unroll") for (int i = 0; i < 4; ++i) _Pragma("unroll") for (      \
      int j = 0; j < 2; ++j) _Pragma("unroll") for (int ks = 0; ks < 2;      \
                                                    ++ks) acc[(MH)*4 + i]    \
      [(NH)*2 + j] = __builtin_amdgcn_mfma_f32_16x16x32_bf16(                \
          af[i][ks], bfv[j][ks], acc[(MH)*4 + i][(NH)*2 + j], 0, 0, 0);      \
  __builtin_amdgcn_s_setprio(0);
#define BAR()                                                               \
  asm volatile("" ::: "memory");                                            \
  __builtin_amdgcn_s_barrier();                                             \
  asm volatile("" ::: "memory");

  for (int t = 0; t < NT; ++t) {
    const int buf = t & 1, nbuf = buf ^ 1;
    const bool pf = (t + 1 < NT);
    const bf* aBase = smem + buf * 32768 + wm * 8192;
    const bf* bBase =
        smem + buf * 32768 + 16384 + (wn >> 1) * 8192 + (wn & 1) * 4096;
    // phase 1: (mh0, nh0); stage A-half0
    RD_A(0);
    RD_B(0);
    if (pf) stageH(nbuf, 0, 0, t + 1);
    BAR();
    MM16(0, 0);
    BAR();
    // phase 2: (mh0, nh1); stage A-half1  (A regs reused)
    RD_B(1);
    if (pf) stageH(nbuf, 0, 1, t + 1);
    BAR();
    MM16(0, 1);
    BAR();
    // phase 3: (mh1, nh1); stage B-half0  (B regs reused)
    RD_A(1);
    if (pf) stageH(nbuf, 1, 0, t + 1);
    BAR();
    MM16(1, 1);
    BAR();
    // phase 4: (mh1, nh0); stage B-half1
    RD_B(0);
    if (pf) stageH(nbuf, 1, 1, t + 1);
    BAR();
    MM16(1, 0);
    // boundary: own loads drained, then block-wide barrier
    asm volatile("s_waitcnt vmcnt(0)" ::: "memory");
    __builtin_amdgcn_s_barrier();
    asm volatile("" ::: "memory");
  }
#undef RD_A
#undef RD_B
#undef MM16
#undef BAR

  // epilogue: j-inner f32 rows (identical mapping to R12 head)
  int ngj[4];
  float bv[4];
#pragma unroll
  for (int j = 0; j < 4; ++j) {
    ngj[j] = n0 + wn * 64 + j * 16 + lm;
    bv[j] = (ngj[j] < V_) ? bias[ngj[j]] : 0.f;
  }
#pragma unroll
  for (int i = 0; i < 8; ++i)
#pragma unroll
    for (int r = 0; r < 4; ++r) {
      int row = m0 + wm * 128 + i * 16 + lg * 4 + r;
      float* orow = out + (size_t)row * V_;
#pragma unroll
      for (int j = 0; j < 4; ++j)
        if (ngj[j] < V_) orow[ngj[j]] = acc[i][j][r] + bv[j];
    }
}

// ------- flash attention: 2-wave blocks, 2-phase prefetch, XOR swizzle -----
__global__ __launch_bounds__(128) void attn_k(const bf* __restrict__ q,
                                              const bf* __restrict__ k,
                                              const bf* __restrict__ vt,
                                              bf* __restrict__ yb) {
  const int qb = blockIdx.x, bh = blockIdx.y;  // qb: 32-row tile
  const int tid = threadIdx.x, w = tid >> 6, lane = tid & 63;
  const int lm = lane & 15, lg = lane >> 4;
  const int bb = bh / H_, hh = bh % H_;
  __shared__ __align__(16) bf kl[2][64 * 64];
  __shared__ __align__(16) bf vl[2][64 * 64];
  __shared__ __align__(16) bf pl[2][16 * 64];

  const int srcc = ((lane & 7) ^ (lane >> 3)) * 8;  // pre-swizzled source col
  auto stage = [&](int buf, int kb) {
#pragma unroll
    for (int c = 0; c < 4; ++c) {
      int rbase = w * 32 + c * 8;
      gload16(k + ((size_t)bh * T_ + kb * 64 + rbase + (lane >> 3)) * HD_ +
                  srcc,
              &kl[buf][rbase * 64]);
      gload16(vt + ((size_t)bh * HD_ + rbase + (lane >> 3)) * T_ + kb * 64 +
                  srcc,
              &vl[buf][rbase * 64]);
    }
  };

  const int kx = lm & 7;  // read-side involution key (row&7 == lm&7)

  const int qrow = qb * 32 + w * 16 + lm;
  const bf* qbase = q + ((size_t)bh * T_ + qrow) * HD_;
  bf16x8 qf0 = *(const bf16x8*)(qbase + lg * 8);
  bf16x8 qf1 = *(const bf16x8*)(qbase + 32 + lg * 8);

  f32x4 y[4];
#pragma unroll
  for (int i = 0; i < 4; ++i) y[i] = (f32x4){0.f, 0.f, 0.f, 0.f};
  float m_run = NEGBIG_, l_run = 0.f;

  const int kbmax = qb >> 1;
  stage(0, 0);
  __syncthreads();
  int cur = 0;
  for (int kb = 0; kb <= kbmax; ++kb) {
    if (kb < kbmax) stage(cur ^ 1, kb + 1);

    f32x4 s[4];
    __builtin_amdgcn_s_setprio(1);
#pragma unroll
    for (int t = 0; t < 4; ++t) {
      s[t] = (f32x4){0.f, 0.f, 0.f, 0.f};
      bf16x8 a0 =
          *(const bf16x8*)&kl[cur][(t * 16 + lm) * 64 + (lg ^ kx) * 8];
      s[t] = __builtin_amdgcn_mfma_f32_16x16x32_bf16(a0, qf0, s[t], 0, 0, 0);
      bf16x8 a1 =
          *(const bf16x8*)&kl[cur][(t * 16 + lm) * 64 + ((4 + lg) ^ kx) * 8];
      s[t] = __builtin_amdgcn_mfma_f32_16x16x32_bf16(a1, qf1, s[t], 0, 0, 0);
    }
    __builtin_amdgcn_s_setprio(0);

    float mx = NEGBIG_;
#pragma unroll
    for (int t = 0; t < 4; ++t)
#pragma unroll
      for (int r = 0; r < 4; ++r) {
        float v = s[t][r] * SCALE_;
        int kv = kb * 64 + t * 16 + lg * 4 + r;
        if (kv > qrow) v = NEGBIG_;
        s[t][r] = v;
        mx = fmaxf(mx, v);
      }
    mx = fmaxf(mx, __shfl_xor(mx, 16, 64));
    mx = fmaxf(mx, __shfl_xor(mx, 32, 64));
    float mnew = fmaxf(m_run, mx);
    float corr = __expf(m_run - mnew);
    float rs = 0.f;
#pragma unroll
    for (int t = 0; t < 4; ++t)
#pragma unroll
      for (int r = 0; r < 4; ++r) {
        float p = __expf(s[t][r] - mnew);
        s[t][r] = p;
        rs += p;
      }
    rs += __shfl_xor(rs, 16, 64);
    rs += __shfl_xor(rs, 32, 64);
    l_run = l_run * corr + rs;
    m_run = mnew;

#pragma unroll
    for (int t = 0; t < 4; ++t) {
      bf16x4 pk;
#pragma unroll
      for (int r = 0; r < 4; ++r) pk[r] = (bf)s[t][r];
      *(bf16x4*)&pl[w][lm * 64 + ((t * 16 + lg * 4) ^ (kx * 8))] = pk;
    }

    float cy0 = __shfl(corr, lg * 4 + 0, 64);
    float cy1 = __shfl(corr, lg * 4 + 1, 64);
    float cy2 = __shfl(corr, lg * 4 + 2, 64);
    float cy3 = __shfl(corr, lg * 4 + 3, 64);
#pragma unroll
    for (int nt = 0; nt < 4; ++nt) {
      y[nt][0] *= cy0;
      y[nt][1] *= cy1;
      y[nt][2] *= cy2;
      y[nt][3] *= cy3;
    }

    __builtin_amdgcn_s_setprio(1);
#pragma unroll
    for (int nt = 0; nt < 4; ++nt)
#pragma unroll
      for (int ks = 0; ks < 2; ++ks) {
        bf16x8 ap =
            *(const bf16x8*)&pl[w][lm * 64 + ((ks * 32 + lg * 8) ^ (kx * 8))];
        bf16x8 bv = *(const bf16x8*)&vl[cur][(nt * 16 + lm) * 64 +
                                             ((ks * 4 + lg) ^ kx) * 8];
        y[nt] = __builtin_amdgcn_mfma_f32_16x16x32_bf16(ap, bv, y[nt], 0, 0, 0);
      }
    __builtin_amdgcn_s_setprio(0);
    __syncthreads();
    cur ^= 1;
  }

  float ly[4];
#pragma unroll
  for (int r = 0; r < 4; ++r) ly[r] = __shfl(l_run, lg * 4 + r, 64);
#pragma unroll
  for (int nt = 0; nt < 4; ++nt) {
    int cc = hh * 64 + nt * 16 + lm;
#pragma unroll
    for (int r = 0; r < 4; ++r) {
      int qr = qb * 32 + w * 16 + lg * 4 + r;
      yb[((size_t)(bb * T_ + qr)) * C_ + cc] = (bf)(y[nt][r] / ly[r]);
    }
  }
}

// ---------------- launch ----------------
extern "C" void kernel_launch(void* const* d_in, const int* in_sizes, int n_in,
                              void* d_out, int out_size, void* d_ws,
                              size_t ws_size, hipStream_t stream) {
  (void)in_sizes; (void)n_in; (void)out_size;
  const int* tokens = (const int*)d_in[0];
  const float* tok_emb = (const float*)d_in[1];
  const float* pos_emb = (const float*)d_in[2];
  const float* Wq = (const float*)d_in[3];
  const float* Wk = (const float*)d_in[4];
  const float* Wv = (const float*)d_in[5];
  const float* Wo = (const float*)d_in[6];
  const float* bo = (const float*)d_in[7];
  const float* ln1g = (const float*)d_in[8];
  const float* ln1b = (const float*)d_in[9];
  const float* ln2g = (const float*)d_in[10];
  const float* ln2b = (const float*)d_in[11];
  const float* W1 = (const float*)d_in[12];
  const float* b1 = (const float*)d_in[13];
  const float* W2 = (const float*)d_in[14];
  const float* b2 = (const float*)d_in[15];
  const float* lnfg = (const float*)d_in[16];
  const float* lnfb = (const float*)d_in[17];
  const float* headw = (const float*)d_in[18];
  const float* headb = (const float*)d_in[19];
  float* out = (float*)d_out;

  uint8_t* base = (uint8_t*)d_ws;
  size_t off = 0;
  auto alloc = [&](size_t n) -> uint8_t* {
    uint8_t* r = base + off;
    off += (n + 255) & ~(size_t)255;
    return r;
  };
  float* x = (float*)alloc((size_t)BT_ * C_ * 4);
  bf* xb = (bf*)alloc((size_t)BT_ * C_ * 2);
  bf* qq = (bf*)alloc((size_t)BT_ * C_ * 2);
  bf* kk = (bf*)alloc((size_t)BT_ * C_ * 2);
  bf* vt = (bf*)alloc((size_t)BT_ * C_ * 2);
  bf* ybuf = (bf*)alloc((size_t)BT_ * C_ * 2);
  bf* hb = (bf*)alloc((size_t)BT_ * F_ * 2);
  bf* headT = (bf*)alloc((size_t)VP2_ * C_ * 2);
  // weight buffers: hoisted (6 layers) if ws allows, else single-layer
  size_t fixed = off;
  size_t perLayer = ((size_t)3 * C_ * C_ + (size_t)C_ * C_ +
                     (size_t)F_ * C_ * 2) * 2;  // bytes per layer
  bool hoisted = (ws_size >= fixed + (size_t)L_ * perLayer + (4u << 20));
  int nw_lay = hoisted ? L_ : 1;
  bf* wqkvT = (bf*)alloc((size_t)nw_lay * 3 * C_ * C_ * 2);
  bf* woT = (bf*)alloc((size_t)nw_lay * C_ * C_ * 2);
  bf* w1T = (bf*)alloc((size_t)nw_lay * F_ * C_ * 2);
  bf* w2T = (bf*)alloc((size_t)nw_lay * C_ * F_ * 2);

  dim3 blk(256), blk8(512), blk2(128);
  transpose_k<<<dim3(C_ / 64, VP2_ / 64), blk, 0, stream>>>(headw, headT, V_,
                                                            C_, V_);
  if (hoisted) {
    trans_all_k<<<L_ * 1728, blk, 0, stream>>>(Wq, Wk, Wv, Wo, W1, W2, wqkvT,
                                               woT, w1T, w2T);
  }
  embed_k<<<dim3(BT_, 3), blk, 0, stream>>>(tokens, tok_emb, pos_emb, x);

  for (int l = 0; l < L_; ++l) {
    int lw = hoisted ? l : 0;
    bf* qkvT_l = wqkvT + (size_t)lw * 3 * C_ * C_;
    bf* woT_l = woT + (size_t)lw * C_ * C_;
    bf* w1T_l = w1T + (size_t)lw * F_ * C_;
    bf* w2T_l = w2T + (size_t)lw * C_ * F_;
    if (!hoisted) {
      trans_layer_k<<<1728, blk, 0, stream>>>(
          Wq + (size_t)l * H_ * C_ * HD_, Wk + (size_t)l * H_ * C_ * HD_,
          Wv + (size_t)l * H_ * C_ * HD_, Wo + (size_t)l * C_ * C_,
          W1 + (size_t)l * C_ * F_, W2 + (size_t)l * F_ * C_, qkvT_l, woT_l,
          w1T_l, w2T_l);
    }

    ln_k<<<BT_, blk, 0, stream>>>(x, x, xb, ln1g + l * C_, ln1b + l * C_);
    gemm_bt<0, 64, 128, 4, 1><<<dim3(2304 / 128, BT_ / 64), blk, 0, stream>>>(
        xb, qkvT_l, nullptr, nullptr, qq, kk, vt, C_);
    attn_k<<<dim3(T_ / 32, 2 * H_), blk2, 0, stream>>>(qq, kk, vt, ybuf);
    gemm_bt<1, 64, 64, 4, 2>
        <<<dim3(C_ / 64, BT_ / 64, 2), blk, 0, stream>>>(
            ybuf, woT_l, bo + l * C_, x, nullptr, nullptr, nullptr, C_);
    ln_k<<<BT_, blk, 0, stream>>>(x, x, xb, ln2g + l * C_, ln2b + l * C_);
    gemm_bt<2, 128, 128, 8, 1>
        <<<dim3(F_ / 128, BT_ / 128), blk8, 0, stream>>>(
            xb, w1T_l, b1 + l * F_, nullptr, hb, nullptr, nullptr, C_);
    gemm_bt<1, 64, 64, 4, 2>
        <<<dim3(C_ / 64, BT_ / 64, 2), blk, 0, stream>>>(
            hb, w2T_l, b2 + l * C_, x, nullptr, nullptr, nullptr, F_);
  }

  ln_k<<<BT_, blk, 0, stream>>>(x, x, xb, lnfg, lnfb);
  gemm_head8<<<dim3(VP2_ / 256, BT_ / 256), blk8, 0, stream>>>(xb, headT,
                                                               headb, out);
}

// Round 17
// 1168.187 us; speedup vs baseline: 1.0281x; 1.0281x over previous
//
#include <hip/hip_runtime.h>
#include <hip/hip_bf16.h>
#include <stdint.h>
#include <math.h>

// GPT-2-small forward. Inputs f32, compute bf16 MFMA w/ f32 accum, out f32.
// R16: head reverted to R12/R14 gemm_bt<3,256,256,8> (282us proven; 3 failed
//      pipeline attempts close that line). Mid GEMMs QKV/Wo/W2 -> NW=8
//      (doubled waves/SIMD at same tile/LDS; V-epilogue generalized to TPR).

#define L_ 6
#define H_ 12
#define C_ 768
#define T_ 1024
#define V_ 50257
#define VP2_ 50432
#define HD_ 64
#define BT_ 2048
#define F_ 3072
#define SCALE_ 0.03608439182435161f  // 768^-0.5 (reference scales by C, not HD)
#define NEGBIG_ -1e30f

typedef __bf16 bf;
typedef __attribute__((ext_vector_type(8))) __bf16 bf16x8;
typedef __attribute__((ext_vector_type(4))) __bf16 bf16x4;
typedef __attribute__((ext_vector_type(4))) float f32x4;

__device__ __forceinline__ void gload16(const void* g, void* l) {
  __builtin_amdgcn_global_load_lds(
      (const __attribute__((address_space(1))) unsigned int*)g,
      (__attribute__((address_space(3))) unsigned int*)l, 16, 0, 0);
}

__device__ __forceinline__ float gelu_f(float x) {
  return 0.5f * x * (1.0f + erff(x * 0.70710678118654752f));
}

// ---------------- embedding ----------------
__global__ __launch_bounds__(256) void embed_k(const int* __restrict__ tok,
                                               const float* __restrict__ te,
                                               const float* __restrict__ pe,
                                               float* __restrict__ x) {
  int bt = blockIdx.x;
  int c = blockIdx.y * 256 + threadIdx.x;
  int t = bt & (T_ - 1);
  int v = tok[bt];
  x[(size_t)bt * C_ + c] = te[(size_t)v * C_ + c] + pe[(size_t)t * C_ + c];
}

// ---------------- layernorm ----------------
__global__ __launch_bounds__(256) void ln_k(const float* __restrict__ xin,
                                            float* __restrict__ xout,
                                            bf* __restrict__ xb,
                                            const float* __restrict__ g,
                                            const float* __restrict__ b) {
  int row = blockIdx.x;
  const float* xr = xin + (size_t)row * C_;
  int tid = threadIdx.x;
  float v0 = xr[tid], v1 = xr[tid + 256], v2 = xr[tid + 512];
  float s1 = v0 + v1 + v2;
  float s2 = v0 * v0 + v1 * v1 + v2 * v2;
#pragma unroll
  for (int o = 32; o > 0; o >>= 1) {
    s1 += __shfl_xor(s1, o, 64);
    s2 += __shfl_xor(s2, o, 64);
  }
  __shared__ float r1[4], r2[4];
  int w = tid >> 6, lane = tid & 63;
  if (lane == 0) { r1[w] = s1; r2[w] = s2; }
  __syncthreads();
  float S1 = r1[0] + r1[1] + r1[2] + r1[3];
  float S2 = r2[0] + r2[1] + r2[2] + r2[3];
  float mean = S1 * (1.0f / C_);
  float var = S2 * (1.0f / C_) - mean * mean;
  float rs = rsqrtf(fmaxf(var, 0.0f) + 1e-5f);
  float* xo = xout + (size_t)row * C_;
  bf* xbo = xb + (size_t)row * C_;
  float vv[3] = {v0, v1, v2};
#pragma unroll
  for (int j = 0; j < 3; ++j) {
    int c = tid + j * 256;
    float o = (vv[j] - mean) * rs * g[c] + b[c];
    xo[c] = o;
    xbo[c] = (bf)o;
  }
}

// ------- 64x64 tiled transpose + f32->bf16: dst[n][k] = (bf)src[k][n] -------
__device__ __forceinline__ void transpose_body(const float* __restrict__ src,
                                               bf* __restrict__ dst, int src_ld,
                                               int dst_ld, int k0, int n0,
                                               int nmax) {
  __shared__ __align__(16) bf tl[64][72];
  int tid = threadIdx.x;
  int r = tid >> 2;
  int cb = (tid & 3) * 16;
#pragma unroll
  for (int j4 = 0; j4 < 4; ++j4) {
    int c = cb + j4 * 4;
    int n = n0 + c;
    size_t idx = (size_t)(k0 + r) * src_ld + n;
    const float* sp = src + idx;
    if (n + 4 <= nmax && (idx & 3) == 0) {
      f32x4 v = *(const f32x4*)sp;
      tl[r][c] = (bf)v[0];
      tl[r][c + 1] = (bf)v[1];
      tl[r][c + 2] = (bf)v[2];
      tl[r][c + 3] = (bf)v[3];
    } else {
#pragma unroll
      for (int j = 0; j < 4; ++j)
        tl[r][c + j] = (n + j < nmax) ? (bf)sp[j] : (bf)0.0f;
    }
  }
  __syncthreads();
  int n = n0 + r;
  bf16x8 w0, w1;
#pragma unroll
  for (int j = 0; j < 8; ++j) {
    w0[j] = tl[cb + j][r];
    w1[j] = tl[cb + 8 + j][r];
  }
  bf* dp = dst + (size_t)n * dst_ld + k0 + cb;
  *(bf16x8*)dp = w0;
  *(bf16x8*)(dp + 8) = w1;
}

__global__ __launch_bounds__(256) void transpose_k(const float* __restrict__ src,
                                                   bf* __restrict__ dst,
                                                   int src_ld, int dst_ld,
                                                   int nmax) {
  transpose_body(src, dst, src_ld, dst_ld, blockIdx.x * 64, blockIdx.y * 64,
                 nmax);
}

// per-layer weight transpose body: 1728 tiles/layer
__device__ __forceinline__ void trans_layer_body(
    int r, const float* __restrict__ Wq, const float* __restrict__ Wk,
    const float* __restrict__ Wv, const float* __restrict__ Wo,
    const float* __restrict__ W1, const float* __restrict__ W2,
    bf* __restrict__ wqkvT, bf* __restrict__ woT, bf* __restrict__ w1T,
    bf* __restrict__ w2T) {
  if (r < 432) {
    int z = r / 12, k0 = (r % 12) * 64;
    int tsel = z / H_, hh = z % H_;
    const float* W = (tsel == 0) ? Wq : (tsel == 1) ? Wk : Wv;
    transpose_body(W + (size_t)hh * C_ * HD_,
                   wqkvT + (size_t)(tsel * C_ + hh * HD_) * C_, HD_, C_, k0, 0,
                   HD_);
  } else if (r < 576) {
    r -= 432;
    transpose_body(Wo, woT, C_, C_, (r % 12) * 64, (r / 12) * 64, C_);
  } else if (r < 1152) {
    r -= 576;
    transpose_body(W1, w1T, F_, C_, (r % 12) * 64, (r / 12) * 64, F_);
  } else {
    r -= 1152;
    transpose_body(W2, w2T, C_, F_, (r % 48) * 64, (r / 48) * 64, C_);
  }
}

__global__ __launch_bounds__(256) void trans_layer_k(
    const float* __restrict__ Wq, const float* __restrict__ Wk,
    const float* __restrict__ Wv, const float* __restrict__ Wo,
    const float* __restrict__ W1, const float* __restrict__ W2,
    bf* __restrict__ wqkvT, bf* __restrict__ woT, bf* __restrict__ w1T,
    bf* __restrict__ w2T) {
  trans_layer_body(blockIdx.x, Wq, Wk, Wv, Wo, W1, W2, wqkvT, woT, w1T, w2T);
}

// all-layer weight transpose: grid 6*1728 (hoisted path)
__global__ __launch_bounds__(256) void trans_all_k(
    const float* __restrict__ Wq, const float* __restrict__ Wk,
    const float* __restrict__ Wv, const float* __restrict__ Wo,
    const float* __restrict__ W1, const float* __restrict__ W2,
    bf* __restrict__ wqkvT, bf* __restrict__ woT, bf* __restrict__ w1T,
    bf* __restrict__ w2T) {
  int l = blockIdx.x / 1728;
  int r = blockIdx.x % 1728;
  trans_layer_body(r, Wq + (size_t)l * H_ * C_ * HD_,
                   Wk + (size_t)l * H_ * C_ * HD_,
                   Wv + (size_t)l * H_ * C_ * HD_, Wo + (size_t)l * C_ * C_,
                   W1 + (size_t)l * C_ * F_, W2 + (size_t)l * F_ * C_,
                   wqkvT + (size_t)l * 3 * C_ * C_, woT + (size_t)l * C_ * C_,
                   w1T + (size_t)l * F_ * C_, w2T + (size_t)l * C_ * F_);
}

// ---------------- GEMM: C[2048][N] = A[2048][K] * Bt[N][K]^T ----------------
// BK=64, both-sides XOR LDS swizzle, XCD-grouped m-inner block swizzle,
// 2-phase dbuf prefetch. KSPLIT=2: blockIdx.z picks K half; MODE 1 uses
// atomicAdd (bias added by z==0 half only).
template <int MODE, int BM, int BN, int NW, int KSPLIT>
__global__ __launch_bounds__(NW * 64) void gemm_bt(
    const bf* __restrict__ A, const bf* __restrict__ Bt,
    const float* __restrict__ bias, float* __restrict__ xres,
    bf* __restrict__ o0, bf* __restrict__ o1, bf* __restrict__ o2, int K) {
  constexpr int WM = BM / 2;
  constexpr int WN = BN / (NW / 2);
  constexpr int MI = WM / 16, NJ = WN / 16;
  constexpr int HALF = (BM + BN) * 64;
  __shared__ __align__(16) bf smem[2 * HALF];
  const int tid = threadIdx.x;
  const int w = tid >> 6, lane = tid & 63;
  const int wm = (NW == 8) ? (w >> 2) : (w >> 1);
  const int wn = (NW == 8) ? (w & 3) : (w & 1);
  const int lm = lane & 15, lg = lane >> 4;

  const int lin = blockIdx.y * gridDim.x + blockIdx.x;
  const int q8 = (gridDim.x * gridDim.y) >> 3;
  const int wg = (lin & 7) * q8 + (lin >> 3);
  const int mt = gridDim.y;
  const int m0 = (wg % mt) * BM, n0 = (wg / mt) * BN;

  const int kchunk = K / KSPLIT;
  const int kbase = (KSPLIT == 2) ? blockIdx.z * kchunk : 0;

  const int lr8 = lane >> 3;
  const int lc8s = ((lane & 7) ^ lr8) * 8;

  auto stage = [&](int buf, int k0) {
    bf* aL = smem + buf * HALF;
    bf* bL = aL + BM * 64;
#pragma unroll
    for (int c = 0; c < BM / (8 * NW); ++c) {
      int row = c * (8 * NW) + w * 8;
      gload16(A + (size_t)(m0 + row + lr8) * K + k0 + lc8s, &aL[row * 64]);
    }
#pragma unroll
    for (int c = 0; c < BN / (8 * NW); ++c) {
      int row = c * (8 * NW) + w * 8;
      gload16(Bt + (size_t)(n0 + row + lr8) * K + k0 + lc8s, &bL[row * 64]);
    }
  };

  f32x4 acc[MI][NJ];
#pragma unroll
  for (int i = 0; i < MI; ++i)
#pragma unroll
    for (int j = 0; j < NJ; ++j) acc[i][j] = (f32x4){0.f, 0.f, 0.f, 0.f};

  const int cXor = (lm & 7) * 8;
  const int NT = kchunk >> 6;
  stage(0, kbase);
  __syncthreads();
  int cur = 0;
  for (int t = 0; t < NT; ++t) {
    if (t + 1 < NT) stage(cur ^ 1, kbase + ((t + 1) << 6));
    const bf* aL = smem + cur * HALF;
    const bf* bL = aL + BM * 64;
#pragma unroll
    for (int ks = 0; ks < 2; ++ks) {
      const int cc = (ks * 32 + lg * 8) ^ cXor;
      bf16x8 af[MI], bfv[NJ];
#pragma unroll
      for (int i = 0; i < MI; ++i)
        af[i] = *(const bf16x8*)&aL[(wm * WM + i * 16 + lm) * 64 + cc];
#pragma unroll
      for (int j = 0; j < NJ; ++j)
        bfv[j] = *(const bf16x8*)&bL[(wn * WN + j * 16 + lm) * 64 + cc];
      __builtin_amdgcn_s_setprio(1);
#pragma unroll
      for (int i = 0; i < MI; ++i)
#pragma unroll
        for (int j = 0; j < NJ; ++j)
          acc[i][j] = __builtin_amdgcn_mfma_f32_16x16x32_bf16(
              af[i], bfv[j], acc[i][j], 0, 0, 0);
      __builtin_amdgcn_s_setprio(0);
    }
    __syncthreads();  // drains next-tile vmcnt + barrier
    cur ^= 1;
  }

  if constexpr (MODE == 3) {
    int ngj[NJ];
    float bv[NJ];
#pragma unroll
    for (int j = 0; j < NJ; ++j) {
      ngj[j] = n0 + wn * WN + j * 16 + lm;
      bv[j] = (ngj[j] < V_) ? bias[ngj[j]] : 0.f;
    }
#pragma unroll
    for (int i = 0; i < MI; ++i)
#pragma unroll
      for (int r = 0; r < 4; ++r) {
        int row = m0 + wm * WM + i * 16 + lg * 4 + r;
        float* orow = xres + (size_t)row * V_;
#pragma unroll
        for (int j = 0; j < NJ; ++j)
          if (ngj[j] < V_) orow[ngj[j]] = acc[i][j][r] + bv[j];
      }
    return;
  }

  if constexpr (MODE == 0) {
    const int bb = m0 >> 10;
    if (n0 >= 2 * C_) {
      // V: stage [d][t] in LDS (stride BM+8), TPR threads per d-row
      bf* sv = smem;
#pragma unroll
      for (int i = 0; i < MI; ++i)
#pragma unroll
        for (int j = 0; j < NJ; ++j) {
          int dl = wn * WN + j * 16 + lm;
#pragma unroll
          for (int r = 0; r < 4; ++r) {
            int tl = wm * WM + i * 16 + lg * 4 + r;
            sv[dl * (BM + 8) + tl] = (bf)acc[i][j][r];
          }
        }
      __syncthreads();
      constexpr int TPR = (NW * 64) / BN;     // threads per d-row
      constexpr int CP = BM / TPR;            // cols per thread
      int dd_l = tid / TPR;
      int part = tid % TPR;
      size_t vrow = (size_t)bb * C_ + (n0 - 2 * C_) + dd_l;
      int t_base = m0 & (T_ - 1);
#pragma unroll
      for (int s = 0; s < CP / 8; ++s) {
        int tt = part * CP + s * 8;
        *(bf16x8*)(o2 + vrow * T_ + t_base + tt) =
            *(const bf16x8*)&sv[dd_l * (BM + 8) + tt];
      }
      return;
    }
    // Q / K direct, j-inner
    bf* dst = (n0 < C_) ? o0 : o1;
    int nb = (n0 < C_) ? n0 : n0 - C_;
    size_t basej[NJ];
#pragma unroll
    for (int j = 0; j < NJ; ++j) {
      int rr = nb + wn * WN + j * 16 + lm;
      int hh = rr >> 6, dd = rr & 63;
      basej[j] = ((size_t)(bb * H_ + hh) * T_) * HD_ + dd;
    }
#pragma unroll
    for (int i = 0; i < MI; ++i)
#pragma unroll
      for (int r = 0; r < 4; ++r) {
        int tt = (m0 + wm * WM + i * 16 + lg * 4 + r) & (T_ - 1);
#pragma unroll
        for (int j = 0; j < NJ; ++j)
          dst[basej[j] + (size_t)tt * HD_] = (bf)acc[i][j][r];
      }
    return;
  }

  // MODE 1 / MODE 2, j-inner
  int ngj[NJ];
  float bv[NJ];
#pragma unroll
  for (int j = 0; j < NJ; ++j) {
    ngj[j] = n0 + wn * WN + j * 16 + lm;
    bv[j] = (KSPLIT == 1 || blockIdx.z == 0) ? bias[ngj[j]] : 0.f;
  }
#pragma unroll
  for (int i = 0; i < MI; ++i)
#pragma unroll
    for (int r = 0; r < 4; ++r) {
      int row = m0 + wm * WM + i * 16 + lg * 4 + r;
      if constexpr (MODE == 1) {
        float* xrow = xres + (size_t)row * C_;
#pragma unroll
        for (int j = 0; j < NJ; ++j) {
          if constexpr (KSPLIT == 2)
            atomicAdd(&xrow[ngj[j]], acc[i][j][r] + bv[j]);
          else
            xrow[ngj[j]] += acc[i][j][r] + bv[j];
        }
      } else {
        bf* orow = o0 + (size_t)row * F_;
#pragma unroll
        for (int j = 0; j < NJ; ++j)
          orow[ngj[j]] = (bf)gelu_f(acc[i][j][r] + bv[j]);
      }
    }
}

// ------- flash attention: 2-wave blocks, 2-phase prefetch, XOR swizzle -----
__global__ __launch_bounds__(128) void attn_k(const bf* __restrict__ q,
                                              const bf* __restrict__ k,
                                              const bf* __restrict__ vt,
                                              bf* __restrict__ yb) {
  const int qb = blockIdx.x, bh = blockIdx.y;  // qb: 32-row tile
  const int tid = threadIdx.x, w = tid >> 6, lane = tid & 63;
  const int lm = lane & 15, lg = lane >> 4;
  const int bb = bh / H_, hh = bh % H_;
  __shared__ __align__(16) bf kl[2][64 * 64];
  __shared__ __align__(16) bf vl[2][64 * 64];
  __shared__ __align__(16) bf pl[2][16 * 64];

  const int srcc = ((lane & 7) ^ (lane >> 3)) * 8;  // pre-swizzled source col
  auto stage = [&](int buf, int kb) {
#pragma unroll
    for (int c = 0; c < 4; ++c) {
      int rbase = w * 32 + c * 8;
      gload16(k + ((size_t)bh * T_ + kb * 64 + rbase + (lane >> 3)) * HD_ +
                  srcc,
              &kl[buf][rbase * 64]);
      gload16(vt + ((size_t)bh * HD_ + rbase + (lane >> 3)) * T_ + kb * 64 +
                  srcc,
              &vl[buf][rbase * 64]);
    }
  };

  const int kx = lm & 7;  // read-side involution key (row&7 == lm&7)

  const int qrow = qb * 32 + w * 16 + lm;
  const bf* qbase = q + ((size_t)bh * T_ + qrow) * HD_;
  bf16x8 qf0 = *(const bf16x8*)(qbase + lg * 8);
  bf16x8 qf1 = *(const bf16x8*)(qbase + 32 + lg * 8);

  f32x4 y[4];
#pragma unroll
  for (int i = 0; i < 4; ++i) y[i] = (f32x4){0.f, 0.f, 0.f, 0.f};
  float m_run = NEGBIG_, l_run = 0.f;

  const int kbmax = qb >> 1;
  stage(0, 0);
  __syncthreads();
  int cur = 0;
  for (int kb = 0; kb <= kbmax; ++kb) {
    if (kb < kbmax) stage(cur ^ 1, kb + 1);

    f32x4 s[4];
    __builtin_amdgcn_s_setprio(1);
#pragma unroll
    for (int t = 0; t < 4; ++t) {
      s[t] = (f32x4){0.f, 0.f, 0.f, 0.f};
      bf16x8 a0 =
          *(const bf16x8*)&kl[cur][(t * 16 + lm) * 64 + (lg ^ kx) * 8];
      s[t] = __builtin_amdgcn_mfma_f32_16x16x32_bf16(a0, qf0, s[t], 0, 0, 0);
      bf16x8 a1 =
          *(const bf16x8*)&kl[cur][(t * 16 + lm) * 64 + ((4 + lg) ^ kx) * 8];
      s[t] = __builtin_amdgcn_mfma_f32_16x16x32_bf16(a1, qf1, s[t], 0, 0, 0);
    }
    __builtin_amdgcn_s_setprio(0);

    float mx = NEGBIG_;
#pragma unroll
    for (int t = 0; t < 4; ++t)
#pragma unroll
      for (int r = 0; r < 4; ++r) {
        float v = s[t][r] * SCALE_;
        int kv = kb * 64 + t * 16 + lg * 4 + r;
        if (kv > qrow) v = NEGBIG_;
        s[t][r] = v;
        mx = fmaxf(mx, v);
      }
    mx = fmaxf(mx, __shfl_xor(mx, 16, 64));
    mx = fmaxf(mx, __shfl_xor(mx, 32, 64));
    float mnew = fmaxf(m_run, mx);
    float corr = __expf(m_run - mnew);
    float rs = 0.f;
#pragma unroll
    for (int t = 0; t < 4; ++t)
#pragma unroll
      for (int r = 0; r < 4; ++r) {
        float p = __expf(s[t][r] - mnew);
        s[t][r] = p;
        rs += p;
      }
    rs += __shfl_xor(rs, 16, 64);
    rs += __shfl_xor(rs, 32, 64);
    l_run = l_run * corr + rs;
    m_run = mnew;

#pragma unroll
    for (int t = 0; t < 4; ++t) {
      bf16x4 pk;
#pragma unroll
      for (int r = 0; r < 4; ++r) pk[r] = (bf)s[t][r];
      *(bf16x4*)&pl[w][lm * 64 + ((t * 16 + lg * 4) ^ (kx * 8))] = pk;
    }

    float cy0 = __shfl(corr, lg * 4 + 0, 64);
    float cy1 = __shfl(corr, lg * 4 + 1, 64);
    float cy2 = __shfl(corr, lg * 4 + 2, 64);
    float cy3 = __shfl(corr, lg * 4 + 3, 64);
#pragma unroll
    for (int nt = 0; nt < 4; ++nt) {
      y[nt][0] *= cy0;
      y[nt][1] *= cy1;
      y[nt][2] *= cy2;
      y[nt][3] *= cy3;
    }

    __builtin_amdgcn_s_setprio(1);
#pragma unroll
    for (int nt = 0; nt < 4; ++nt)
#pragma unroll
      for (int ks = 0; ks < 2; ++ks) {
        bf16x8 ap =
            *(const bf16x8*)&pl[w][lm * 64 + ((ks * 32 + lg * 8) ^ (kx * 8))];
        bf16x8 bv = *(const bf16x8*)&vl[cur][(nt * 16 + lm) * 64 +
                                             ((ks * 4 + lg) ^ kx) * 8];
        y[nt] = __builtin_amdgcn_mfma_f32_16x16x32_bf16(ap, bv, y[nt], 0, 0, 0);
      }
    __builtin_amdgcn_s_setprio(0);
    __syncthreads();
    cur ^= 1;
  }

  float ly[4];
#pragma unroll
  for (int r = 0; r < 4; ++r) ly[r] = __shfl(l_run, lg * 4 + r, 64);
#pragma unroll
  for (int nt = 0; nt < 4; ++nt) {
    int cc = hh * 64 + nt * 16 + lm;
#pragma unroll
    for (int r = 0; r < 4; ++r) {
      int qr = qb * 32 + w * 16 + lg * 4 + r;
      yb[((size_t)(bb * T_ + qr)) * C_ + cc] = (bf)(y[nt][r] / ly[r]);
    }
  }
}

// ---------------- launch ----------------
extern "C" void kernel_launch(void* const* d_in, const int* in_sizes, int n_in,
                              void* d_out, int out_size, void* d_ws,
                              size_t ws_size, hipStream_t stream) {
  (void)in_sizes; (void)n_in; (void)out_size;
  const int* tokens = (const int*)d_in[0];
  const float* tok_emb = (const float*)d_in[1];
  const float* pos_emb = (const float*)d_in[2];
  const float* Wq = (const float*)d_in[3];
  const float* Wk = (const float*)d_in[4];
  const float* Wv = (const float*)d_in[5];
  const float* Wo = (const float*)d_in[6];
  const float* bo = (const float*)d_in[7];
  const float* ln1g = (const float*)d_in[8];
  const float* ln1b = (const float*)d_in[9];
  const float* ln2g = (const float*)d_in[10];
  const float* ln2b = (const float*)d_in[11];
  const float* W1 = (const float*)d_in[12];
  const float* b1 = (const float*)d_in[13];
  const float* W2 = (const float*)d_in[14];
  const float* b2 = (const float*)d_in[15];
  const float* lnfg = (const float*)d_in[16];
  const float* lnfb = (const float*)d_in[17];
  const float* headw = (const float*)d_in[18];
  const float* headb = (const float*)d_in[19];
  float* out = (float*)d_out;

  uint8_t* base = (uint8_t*)d_ws;
  size_t off = 0;
  auto alloc = [&](size_t n) -> uint8_t* {
    uint8_t* r = base + off;
    off += (n + 255) & ~(size_t)255;
    return r;
  };
  float* x = (float*)alloc((size_t)BT_ * C_ * 4);
  bf* xb = (bf*)alloc((size_t)BT_ * C_ * 2);
  bf* qq = (bf*)alloc((size_t)BT_ * C_ * 2);
  bf* kk = (bf*)alloc((size_t)BT_ * C_ * 2);
  bf* vt = (bf*)alloc((size_t)BT_ * C_ * 2);
  bf* ybuf = (bf*)alloc((size_t)BT_ * C_ * 2);
  bf* hb = (bf*)alloc((size_t)BT_ * F_ * 2);
  bf* headT = (bf*)alloc((size_t)VP2_ * C_ * 2);
  // weight buffers: hoisted (6 layers) if ws allows, else single-layer
  size_t fixed = off;
  size_t perLayer = ((size_t)3 * C_ * C_ + (size_t)C_ * C_ +
                     (size_t)F_ * C_ * 2) * 2;  // bytes per layer
  bool hoisted = (ws_size >= fixed + (size_t)L_ * perLayer + (4u << 20));
  int nw_lay = hoisted ? L_ : 1;
  bf* wqkvT = (bf*)alloc((size_t)nw_lay * 3 * C_ * C_ * 2);
  bf* woT = (bf*)alloc((size_t)nw_lay * C_ * C_ * 2);
  bf* w1T = (bf*)alloc((size_t)nw_lay * F_ * C_ * 2);
  bf* w2T = (bf*)alloc((size_t)nw_lay * C_ * F_ * 2);

  dim3 blk(256), blk8(512), blk2(128);
  transpose_k<<<dim3(C_ / 64, VP2_ / 64), blk, 0, stream>>>(headw, headT, V_,
                                                            C_, V_);
  if (hoisted) {
    trans_all_k<<<L_ * 1728, blk, 0, stream>>>(Wq, Wk, Wv, Wo, W1, W2, wqkvT,
                                               woT, w1T, w2T);
  }
  embed_k<<<dim3(BT_, 3), blk, 0, stream>>>(tokens, tok_emb, pos_emb, x);

  for (int l = 0; l < L_; ++l) {
    int lw = hoisted ? l : 0;
    bf* qkvT_l = wqkvT + (size_t)lw * 3 * C_ * C_;
    bf* woT_l = woT + (size_t)lw * C_ * C_;
    bf* w1T_l = w1T + (size_t)lw * F_ * C_;
    bf* w2T_l = w2T + (size_t)lw * C_ * F_;
    if (!hoisted) {
      trans_layer_k<<<1728, blk, 0, stream>>>(
          Wq + (size_t)l * H_ * C_ * HD_, Wk + (size_t)l * H_ * C_ * HD_,
          Wv + (size_t)l * H_ * C_ * HD_, Wo + (size_t)l * C_ * C_,
          W1 + (size_t)l * C_ * F_, W2 + (size_t)l * F_ * C_, qkvT_l, woT_l,
          w1T_l, w2T_l);
    }

    ln_k<<<BT_, blk, 0, stream>>>(x, x, xb, ln1g + l * C_, ln1b + l * C_);
    gemm_bt<0, 64, 128, 8, 1><<<dim3(2304 / 128, BT_ / 64), blk8, 0, stream>>>(
        xb, qkvT_l, nullptr, nullptr, qq, kk, vt, C_);
    attn_k<<<dim3(T_ / 32, 2 * H_), blk2, 0, stream>>>(qq, kk, vt, ybuf);
    gemm_bt<1, 64, 64, 8, 2>
        <<<dim3(C_ / 64, BT_ / 64, 2), blk8, 0, stream>>>(
            ybuf, woT_l, bo + l * C_, x, nullptr, nullptr, nullptr, C_);
    ln_k<<<BT_, blk, 0, stream>>>(x, x, xb, ln2g + l * C_, ln2b + l * C_);
    gemm_bt<2, 128, 128, 8, 1>
        <<<dim3(F_ / 128, BT_ / 128), blk8, 0, stream>>>(
            xb, w1T_l, b1 + l * F_, nullptr, hb, nullptr, nullptr, C_);
    gemm_bt<1, 64, 64, 8, 2>
        <<<dim3(C_ / 64, BT_ / 64, 2), blk8, 0, stream>>>(
            hb, w2T_l, b2 + l * C_, x, nullptr, nullptr, nullptr, F_);
  }

  ln_k<<<BT_, blk, 0, stream>>>(x, x, xb, lnfg, lnfb);
  gemm_bt<3, 256, 256, 8, 1><<<dim3(VP2_ / 256, BT_ / 256), blk8, 0, stream>>>(
      xb, headT, headb, out, nullptr, nullptr, nullptr, C_);
}